// Round 2
// baseline (1591.578 us; speedup 1.0000x reference)
//
#include <hip/hip_runtime.h>
#include <hip/hip_bf16.h>

// Problem constants (fixed by the reference)
#define NN 50000
#define EE 800000
#define DIN 146
#define DD 128
#define GG 64
#define LL 4
#define NC 10
#define BN_EPS 1e-5f

__device__ __forceinline__ float bf2f(__hip_bfloat16 v) { return __bfloat162float(v); }

// flag-driven float load: f32!=0 -> buffer is float32, else bf16
__device__ __forceinline__ float loadf(const void* p, long i, int f32) {
    return f32 ? ((const float*)p)[i] : bf2f(((const __hip_bfloat16*)p)[i]);
}

// flags[0]=edge_index int64, flags[1]=batch int64, flags[2]=floats are f32
__global__ void detect_kernel(const void* ei, const void* batch, const void* Wemb,
                              int* __restrict__ flags) {
    __shared__ int s_edge_nz, s_batch_nz, s_f32_cnt;
    int t = threadIdx.x;  // 64 threads
    if (t == 0) { s_edge_nz = 0; s_batch_nz = 0; s_f32_cnt = 0; }
    __syncthreads();
    {   // edge_index: odd 32-bit words spread over [0, 2E). int64 => high halves == 0.
        const int* w = (const int*)ei;
        long j = ((long)t * ((2L * EE) / 64)) | 1;
        if (w[j] != 0) atomicAdd(&s_edge_nz, 1);
    }
    {   // batch: odd words over [N/2, N). sorted int32 values there are > 0.
        const int* w = (const int*)batch;
        long j = ((long)(NN / 2) + (long)t * ((NN / 2) / 64)) | 1;
        if (j < NN && w[j] != 0) atomicAdd(&s_batch_nz, 1);
    }
    {   // W_emb even 16-bit words: bf16 storage => |v| < 2 always; f32 => random exponents.
        const unsigned short* w = (const unsigned short*)Wemb;
        unsigned short v = w[2 * t];
        int ex = (v >> 7) & 0xFF;
        if (v != 0 && ex >= 128) atomicAdd(&s_f32_cnt, 1);
    }
    __syncthreads();
    if (t == 0) {
        flags[0] = (s_edge_nz == 0) ? 1 : 0;
        flags[1] = (s_batch_nz == 0) ? 1 : 0;
        flags[2] = (s_f32_cnt >= 8) ? 1 : 0;
    }
}

__global__ void conv_idx_kernel(const void* ei, const int* __restrict__ flags,
                                int* __restrict__ src32, int* __restrict__ dst32) {
    int e = blockIdx.x * blockDim.x + threadIdx.x;
    if (e >= EE) return;
    const int* w = (const int*)ei;
    int s, d;
    if (flags[0]) { s = w[2L * e]; d = w[2L * (EE + e)]; }
    else          { s = w[e];      d = w[EE + e]; }
    src32[e] = s; dst32[e] = d;
}

__global__ void conv_batch_kernel(const void* b, const int* __restrict__ flags,
                                  int* __restrict__ b32) {
    int i = blockIdx.x * blockDim.x + threadIdx.x;
    if (i >= NN) return;
    b32[i] = flags[1] ? ((const int*)b)[2L * i] : ((const int*)b)[i];
}

// zero deg/cursor/bn accumulators (replaces hipMemsetAsync)
__global__ void init_kernel(int* __restrict__ deg, int* __restrict__ cursor,
                            float* __restrict__ bnacc) {
    int i = blockIdx.x * blockDim.x + threadIdx.x;
    if (i < NN) { deg[i] = 0; cursor[i] = 0; }
    if (i < LL * 256) bnacc[i] = 0.0f;
}

__global__ void deg_kernel(const int* __restrict__ dst, int* __restrict__ deg, int E) {
    int e = blockIdx.x * blockDim.x + threadIdx.x;
    if (e >= E) return;
    int d = dst[e];
    if ((unsigned)d < (unsigned)NN) atomicAdd(&deg[d], 1);
}

__global__ void dinv_kernel(const int* __restrict__ deg, float* __restrict__ dinv, int n) {
    int i = blockIdx.x * blockDim.x + threadIdx.x;
    if (i < n) dinv[i] = rsqrtf((float)(deg[i] + 1));  // +1 self-loop
}

// exclusive prefix sum of cnt[0..n) -> off[0..n], single block of 1024
__global__ void scan_kernel(const int* __restrict__ cnt, int* __restrict__ off, int n) {
    __shared__ int buf[1024];
    __shared__ int carry;
    if (threadIdx.x == 0) carry = 0;
    __syncthreads();
    for (int base = 0; base < n; base += 1024) {
        int i = base + (int)threadIdx.x;
        int v = (i < n) ? cnt[i] : 0;
        buf[threadIdx.x] = v;
        __syncthreads();
        for (int s = 1; s < 1024; s <<= 1) {
            int t = (threadIdx.x >= (unsigned)s) ? buf[threadIdx.x - s] : 0;
            __syncthreads();
            buf[threadIdx.x] += t;
            __syncthreads();
        }
        int incl = buf[threadIdx.x];
        int total = buf[1023];
        int excl = incl - v;
        if (i < n) off[i] = carry + excl;
        __syncthreads();
        if (threadIdx.x == 0) carry += total;
        __syncthreads();
    }
    if (threadIdx.x == 0) off[n] = carry;
}

__global__ void scatter_kernel(const int* __restrict__ src, const int* __restrict__ dst,
                               const int* __restrict__ off, int* __restrict__ cursor,
                               const float* __restrict__ dinv,
                               int* __restrict__ src_s, float* __restrict__ norm_s, int E) {
    int e = blockIdx.x * blockDim.x + threadIdx.x;
    if (e >= E) return;
    int s = src[e], d = dst[e];
    if ((unsigned)s >= (unsigned)NN || (unsigned)d >= (unsigned)NN) return;
    int pos = off[d] + atomicAdd(&cursor[d], 1);
    src_s[pos] = s;
    norm_s[pos] = dinv[s] * dinv[d];
}

// h[r][c] = b[c] + sum_k x[r][k] * W[k][c]
__global__ void emb_kernel(const void* __restrict__ x, const void* __restrict__ W,
                           const void* __restrict__ b, const int* __restrict__ flags,
                           float* __restrict__ h) {
    int f32 = flags[2];
    int r = blockIdx.x;
    int c = threadIdx.x;
    __shared__ float xs[DIN];
    xs[c] = loadf(x, (long)r * DIN + c, f32);
    if (c + 128 < DIN) xs[c + 128] = loadf(x, (long)r * DIN + c + 128, f32);
    __syncthreads();
    float acc = loadf(b, c, f32);
    #pragma unroll 8
    for (int k = 0; k < DIN; ++k) acc += xs[k] * loadf(W, (long)k * DD + c, f32);
    h[(long)r * DD + c] = acc;
}

// m[r][c] = sum_k h[r][k] * Wg[l][k][c]   (layer offset computed in-kernel)
__global__ void mm_kernel(const float* __restrict__ h, const void* __restrict__ Wg,
                          int layer, const int* __restrict__ flags, float* __restrict__ m) {
    int f32 = flags[2];
    long wbase = (long)layer * DD * DD;
    int r = blockIdx.x;
    int c = threadIdx.x;
    __shared__ float hs[DD];
    hs[c] = h[(long)r * DD + c];
    __syncthreads();
    float acc = 0.0f;
    #pragma unroll 8
    for (int k = 0; k < DD; ++k) acc += hs[k] * loadf(Wg, wbase + (long)k * DD + c, f32);
    m[(long)r * DD + c] = acc;
}

// agg[i][c] = dinv[i]^2 * m[i][c] + b[l][c] + sum_{e in CSR(i)} norm[e]*m[src[e]][c]
__global__ void agg_kernel(const float* __restrict__ m,
                           const int* __restrict__ off, const int* __restrict__ src_s,
                           const float* __restrict__ norm_s, const float* __restrict__ dinv,
                           const void* __restrict__ b, int layer,
                           const int* __restrict__ flags, float* __restrict__ agg) {
    int f32 = flags[2];
    int i = blockIdx.x;
    int c = threadIdx.x;
    float di = dinv[i];
    float acc = di * di * m[(long)i * DD + c] + loadf(b, (long)layer * DD + c, f32);
    int e0 = off[i], e1 = off[i + 1];
    for (int e = e0; e < e1; ++e) {
        int j = src_s[e];
        if ((unsigned)j < (unsigned)NN) acc += norm_s[e] * m[(long)j * DD + c];
    }
    agg[(long)i * DD + c] = acc;
}

// column sums + sumsq into acc[0..127]=sum, acc[128..255]=sumsq (pre-zeroed)
__global__ void stats_kernel(const float* __restrict__ agg, float* __restrict__ acc, int n) {
    int c = threadIdx.x & 127;
    int half = threadIdx.x >> 7;  // 0/1
    int rows_per_block = (n + gridDim.x - 1) / gridDim.x;
    int r0 = blockIdx.x * rows_per_block;
    int r1 = min(n, r0 + rows_per_block);
    float s = 0.0f, s2 = 0.0f;
    for (int r = r0 + half; r < r1; r += 2) {
        float v = agg[(long)r * DD + c];
        s += v; s2 += v * v;
    }
    __shared__ float sb[256], sb2[256];
    sb[threadIdx.x] = s; sb2[threadIdx.x] = s2;
    __syncthreads();
    if (threadIdx.x < 128) {
        atomicAdd(&acc[c], sb[threadIdx.x] + sb[threadIdx.x + 128]);
        atomicAdd(&acc[128 + c], sb2[threadIdx.x] + sb2[threadIdx.x + 128]);
    }
}

// h[idx] += relu((agg-mu)*rsqrt(var+eps)*gamma[l] + beta[l])
__global__ void bnapply_kernel(float* __restrict__ h, const float* __restrict__ agg,
                               const float* __restrict__ acc,
                               const void* __restrict__ gamma, const void* __restrict__ beta,
                               int layer, const int* __restrict__ flags, int n) {
    int f32 = flags[2];
    long idx = (long)blockIdx.x * blockDim.x + threadIdx.x;
    if (idx >= (long)n * DD) return;
    int c = (int)(idx & 127);
    float inv_n = 1.0f / (float)n;
    float mu = acc[c] * inv_n;
    float var = acc[128 + c] * inv_n - mu * mu;
    float v = (agg[idx] - mu) * rsqrtf(var + BN_EPS) * loadf(gamma, (long)layer * DD + c, f32)
              + loadf(beta, (long)layer * DD + c, f32);
    h[idx] += fmaxf(v, 0.0f);
}

__device__ int lower_bound_i(const int* __restrict__ a, int n, int v) {
    int lo = 0, hi = n;
    while (lo < hi) {
        int mid = (lo + hi) >> 1;
        if (a[mid] < v) lo = mid + 1; else hi = mid;
    }
    return lo;
}

__global__ void pool_kernel(const float* __restrict__ h, const int* __restrict__ batch,
                            float* __restrict__ hg, int n) {
    int g = blockIdx.x;
    int c = threadIdx.x;
    int lo = lower_bound_i(batch, n, g);
    int hi = lower_bound_i(batch, n, g + 1);
    float s = 0.0f;
    for (int r = lo; r < hi; ++r) s += h[(long)r * DD + c];
    hg[g * DD + c] = s / fmaxf((float)(hi - lo), 1.0f);
}

__global__ void readout_kernel(const float* __restrict__ hg,
                               const void* __restrict__ W1, const void* __restrict__ b1,
                               const void* __restrict__ W2, const void* __restrict__ b2,
                               const void* __restrict__ W3, const void* __restrict__ b3,
                               const int* __restrict__ flags, void* __restrict__ out) {
    int f32 = flags[2];
    int g = blockIdx.x;
    int t = threadIdx.x;
    __shared__ float hgs[DD];
    __shared__ float z1[DD / 2];
    __shared__ float z2[DD / 4];
    hgs[t] = hg[g * DD + t];
    __syncthreads();
    if (t < DD / 2) {
        float acc = loadf(b1, t, f32);
        #pragma unroll 8
        for (int k = 0; k < DD; ++k) acc += hgs[k] * loadf(W1, (long)k * (DD / 2) + t, f32);
        z1[t] = fmaxf(acc, 0.0f);
    }
    __syncthreads();
    if (t < DD / 4) {
        float acc = loadf(b2, t, f32);
        #pragma unroll 8
        for (int k = 0; k < DD / 2; ++k) acc += z1[k] * loadf(W2, (long)k * (DD / 4) + t, f32);
        z2[t] = fmaxf(acc, 0.0f);
    }
    __syncthreads();
    if (t < NC) {
        float acc = loadf(b3, t, f32);
        #pragma unroll 8
        for (int k = 0; k < DD / 4; ++k) acc += z2[k] * loadf(W3, (long)k * NC + t, f32);
        if (f32) ((float*)out)[g * NC + t] = acc;
        else     ((__hip_bfloat16*)out)[g * NC + t] = __float2bfloat16(acc);
    }
}

extern "C" void kernel_launch(void* const* d_in, const int* in_sizes, int n_in,
                              void* d_out, int out_size, void* d_ws, size_t ws_size,
                              hipStream_t stream) {
    const void* x      = d_in[0];
    const void* ei     = d_in[1];
    const void* batch  = d_in[2];
    const void* W_emb  = d_in[3];
    const void* b_emb  = d_in[4];
    const void* W_gcn  = d_in[5];   // [L,128,128]
    const void* b_gcn  = d_in[6];   // [L,128]
    const void* bn_g   = d_in[7];
    const void* bn_b   = d_in[8];
    const void* W_r1   = d_in[9];
    const void* b_r1   = d_in[10];
    const void* W_r2   = d_in[11];
    const void* b_r2   = d_in[12];
    const void* W_r3   = d_in[13];
    const void* b_r3   = d_in[14];

    char* p = (char*)d_ws;
    auto alloc = [&](size_t bytes) -> void* {
        void* r = (void*)p;
        p += (bytes + 255) & ~(size_t)255;
        return r;
    };
    int*   flags  = (int*)alloc(64 * 4);
    int*   deg    = (int*)alloc((size_t)NN * 4);
    int*   cursor = (int*)alloc((size_t)NN * 4);
    float* bnacc  = (float*)alloc((size_t)LL * 256 * 4);
    int*   off    = (int*)alloc((size_t)(NN + 1) * 4);
    float* dinv   = (float*)alloc((size_t)NN * 4);
    int*   src32  = (int*)alloc((size_t)EE * 4);
    int*   dst32  = (int*)alloc((size_t)EE * 4);
    int*   b32    = (int*)alloc((size_t)NN * 4);
    int*   src_s  = (int*)alloc((size_t)EE * 4);
    float* norm_s = (float*)alloc((size_t)EE * 4);
    float* h      = (float*)alloc((size_t)NN * DD * 4);
    float* m      = (float*)alloc((size_t)NN * DD * 4);
    float* agg    = (float*)alloc((size_t)NN * DD * 4);
    float* hg     = (float*)alloc((size_t)GG * DD * 4);

    detect_kernel<<<1, 64, 0, stream>>>(ei, batch, W_emb, flags);
    init_kernel<<<(NN + 255) / 256, 256, 0, stream>>>(deg, cursor, bnacc);
    conv_idx_kernel<<<(EE + 255) / 256, 256, 0, stream>>>(ei, flags, src32, dst32);
    conv_batch_kernel<<<(NN + 255) / 256, 256, 0, stream>>>(batch, flags, b32);

    deg_kernel<<<(EE + 255) / 256, 256, 0, stream>>>(dst32, deg, EE);
    dinv_kernel<<<(NN + 255) / 256, 256, 0, stream>>>(deg, dinv, NN);
    scan_kernel<<<1, 1024, 0, stream>>>(deg, off, NN);
    scatter_kernel<<<(EE + 255) / 256, 256, 0, stream>>>(src32, dst32, off, cursor, dinv,
                                                         src_s, norm_s, EE);
    emb_kernel<<<NN, DD, 0, stream>>>(x, W_emb, b_emb, flags, h);

    for (int l = 0; l < LL; ++l) {
        mm_kernel<<<NN, DD, 0, stream>>>(h, W_gcn, l, flags, m);
        agg_kernel<<<NN, DD, 0, stream>>>(m, off, src_s, norm_s, dinv, b_gcn, l, flags, agg);
        stats_kernel<<<512, 256, 0, stream>>>(agg, bnacc + l * 256, NN);
        bnapply_kernel<<<(NN * DD + 255) / 256, 256, 0, stream>>>(h, agg, bnacc + l * 256,
                                                                  bn_g, bn_b, l, flags, NN);
    }

    pool_kernel<<<GG, DD, 0, stream>>>(h, b32, hg, NN);
    readout_kernel<<<GG, DD, 0, stream>>>(hg, W_r1, b_r1, W_r2, b_r2, W_r3, b_r3, flags, d_out);
}

// Round 3
// 835.684 us; speedup vs baseline: 1.9045x; 1.9045x over previous
//
#include <hip/hip_runtime.h>
#include <hip/hip_bf16.h>

// Problem constants (fixed by the reference)
#define NN 50000
#define EE 800000
#define DIN 146
#define DD 128
#define GG 64
#define LL 4
#define NC 10
#define BN_EPS 1e-5f

#define KS_EMB 148   // 146 padded to multiple of 4

__device__ __forceinline__ float bf2f(__hip_bfloat16 v) { return __bfloat162float(v); }
__device__ __forceinline__ float loadf(const void* p, long i, int f32) {
    return f32 ? ((const float*)p)[i] : bf2f(((const __hip_bfloat16*)p)[i]);
}

// flags[0]=edge_index int64, flags[1]=batch int64, flags[2]=floats are f32
__global__ void detect_kernel(const void* ei, const void* batch, const void* Wemb,
                              int* __restrict__ flags) {
    __shared__ int s_edge_nz, s_batch_nz, s_f32_cnt;
    int t = threadIdx.x;  // 64 threads
    if (t == 0) { s_edge_nz = 0; s_batch_nz = 0; s_f32_cnt = 0; }
    __syncthreads();
    {   const int* w = (const int*)ei;
        long j = ((long)t * ((2L * EE) / 64)) | 1;
        if (w[j] != 0) atomicAdd(&s_edge_nz, 1);
    }
    {   const int* w = (const int*)batch;
        long j = ((long)(NN / 2) + (long)t * ((NN / 2) / 64)) | 1;
        if (j < NN && w[j] != 0) atomicAdd(&s_batch_nz, 1);
    }
    {   const unsigned short* w = (const unsigned short*)Wemb;
        unsigned short v = w[2 * t];
        int ex = (v >> 7) & 0xFF;
        if (v != 0 && ex >= 128) atomicAdd(&s_f32_cnt, 1);
    }
    __syncthreads();
    if (t == 0) {
        flags[0] = (s_edge_nz == 0) ? 1 : 0;
        flags[1] = (s_batch_nz == 0) ? 1 : 0;
        flags[2] = (s_f32_cnt >= 8) ? 1 : 0;
    }
}

// ---- canonicalize params to fp32 (zero-padded to dst_n) ----
struct Param { const void* src; float* dst; int src_n; int dst_n; };
struct Params12 { Param p[12]; };

__global__ void conv_params_kernel(Params12 P, const int* __restrict__ flags) {
    int f32 = flags[2];
    const Param& e = P.p[blockIdx.y];
    int idx = blockIdx.x * 256 + threadIdx.x;
    if (idx < e.dst_n)
        e.dst[idx] = (idx < e.src_n) ? loadf(e.src, idx, f32) : 0.0f;
}

// zero deg/cursor/bnacc/hgsum
__global__ void init_kernel(int* __restrict__ deg, int* __restrict__ cursor,
                            float* __restrict__ bnacc, float* __restrict__ hgsum) {
    int i = blockIdx.x * blockDim.x + threadIdx.x;
    if (i < NN) { deg[i] = 0; cursor[i] = 0; }
    if (i < LL * 256) bnacc[i] = 0.0f;
    if (i < GG * DD) hgsum[i] = 0.0f;
}

// convert edge indices AND build degree histogram in one pass
__global__ void conv_idx_deg_kernel(const void* ei, const int* __restrict__ flags,
                                    int* __restrict__ src32, int* __restrict__ dst32,
                                    int* __restrict__ deg) {
    int e = blockIdx.x * blockDim.x + threadIdx.x;
    if (e >= EE) return;
    const int* w = (const int*)ei;
    int s, d;
    if (flags[0]) { s = w[2L * e]; d = w[2L * (EE + e)]; }
    else          { s = w[e];      d = w[EE + e]; }
    src32[e] = s; dst32[e] = d;
    if ((unsigned)d < (unsigned)NN) atomicAdd(&deg[d], 1);
}

__global__ void conv_batch_kernel(const void* b, const int* __restrict__ flags,
                                  int* __restrict__ b32) {
    int i = blockIdx.x * blockDim.x + threadIdx.x;
    if (i >= NN) return;
    b32[i] = flags[1] ? ((const int*)b)[2L * i] : ((const int*)b)[i];
}

__global__ void dinv_kernel(const int* __restrict__ deg, float* __restrict__ dinv, int n) {
    int i = blockIdx.x * blockDim.x + threadIdx.x;
    if (i < n) dinv[i] = rsqrtf((float)(deg[i] + 1));  // +1 self-loop
}

// ---- 3-phase exclusive scan (shuffle-based, few barriers) ----
__global__ void scan1_kernel(const int* __restrict__ cnt, int* __restrict__ off,
                             int* __restrict__ bsum, int n) {
    int t = threadIdx.x;
    int i = blockIdx.x * 256 + t;
    int v = (i < n) ? cnt[i] : 0;
    int lane = t & 63, w = t >> 6;
    int x = v;
    #pragma unroll
    for (int s = 1; s < 64; s <<= 1) {
        int y = __shfl_up(x, s, 64);
        if (lane >= s) x += y;
    }
    __shared__ int wsum[4];
    if (lane == 63) wsum[w] = x;
    __syncthreads();
    if (t == 0) {
        int a = 0;
        #pragma unroll
        for (int k = 0; k < 4; ++k) { int tmp = wsum[k]; wsum[k] = a; a += tmp; }
        bsum[blockIdx.x] = a;
    }
    __syncthreads();
    int excl = x - v + wsum[w];
    if (i < n) off[i] = excl;
}

__global__ void scan2_kernel(int* __restrict__ bsum, int* __restrict__ boff,
                             int* __restrict__ off_last, int nb) {
    int t = threadIdx.x;  // 256
    int v = (t < nb) ? bsum[t] : 0;
    int lane = t & 63, w = t >> 6;
    int x = v;
    #pragma unroll
    for (int s = 1; s < 64; s <<= 1) {
        int y = __shfl_up(x, s, 64);
        if (lane >= s) x += y;
    }
    __shared__ int wsum[4];
    if (lane == 63) wsum[w] = x;
    __syncthreads();
    __shared__ int total_s;
    if (t == 0) {
        int a = 0;
        #pragma unroll
        for (int k = 0; k < 4; ++k) { int tmp = wsum[k]; wsum[k] = a; a += tmp; }
        total_s = a;
    }
    __syncthreads();
    if (t < nb) boff[t] = x - v + wsum[w];
    if (t == 0) *off_last = total_s;
}

__global__ void scan3_kernel(int* __restrict__ off, const int* __restrict__ boff, int n) {
    int i = blockIdx.x * 256 + threadIdx.x;
    if (i < n) off[i] += boff[blockIdx.x];
}

__global__ void scatter_kernel(const int* __restrict__ src, const int* __restrict__ dst,
                               const int* __restrict__ off, int* __restrict__ cursor,
                               const float* __restrict__ dinv,
                               int* __restrict__ src_s, float* __restrict__ norm_s, int E) {
    int e = blockIdx.x * blockDim.x + threadIdx.x;
    if (e >= E) return;
    int s = src[e], d = dst[e];
    if ((unsigned)s >= (unsigned)NN || (unsigned)d >= (unsigned)NN) return;
    int pos = off[d] + atomicAdd(&cursor[d], 1);
    src_s[pos] = s;
    norm_s[pos] = dinv[s] * dinv[d];
}

// ---- tiled GEMM: C[n x 128] = A[n x K] * W[K x 128] (+bias) ----
// 256 threads, 16 rows/block, 8 outputs/thread.
// mode 0: A is fp32, lda%4==0, float4 staging. mode 1: A is native dtype (flag), scalar staging.
__global__ __launch_bounds__(256) void gemm_kernel(
    const void* __restrict__ A, int lda, int Ks, int Kvalid, int mode,
    const float* __restrict__ W, const float* __restrict__ bias, int has_bias,
    const int* __restrict__ flags, float* __restrict__ C, int n)
{
    __shared__ float As[16 * KS_EMB];
    int t = threadIdx.x;
    int r0 = blockIdx.x * 16;
    if (mode == 0) {
        int nq = Ks >> 2;
        for (int idx = t; idx < 16 * nq; idx += 256) {
            int r = idx / nq, q = idx - r * nq;
            float4 v = make_float4(0.f, 0.f, 0.f, 0.f);
            int row = r0 + r;
            if (row < n) v = *(const float4*)((const float*)A + (long)row * lda + (q << 2));
            *(float4*)&As[r * Ks + (q << 2)] = v;
        }
    } else {
        int f32 = flags[2];
        for (int idx = t; idx < 16 * Ks; idx += 256) {
            int r = idx / Ks, k = idx - r * Ks;
            float v = 0.0f;
            int row = r0 + r;
            if (row < n && k < Kvalid) v = loadf(A, (long)row * lda + k, f32);
            As[r * Ks + k] = v;
        }
    }
    __syncthreads();
    int c = t & 127, rg = t >> 7;
    float binit = has_bias ? bias[c] : 0.0f;
    float acc[8];
    #pragma unroll
    for (int j = 0; j < 8; ++j) acc[j] = binit;
    int nq = Ks >> 2;
    const float* Asr = &As[rg * 8 * Ks];
    for (int q = 0; q < nq; ++q) {
        int k = q << 2;
        float w0 = W[(long)(k + 0) * DD + c];
        float w1 = W[(long)(k + 1) * DD + c];
        float w2 = W[(long)(k + 2) * DD + c];
        float w3 = W[(long)(k + 3) * DD + c];
        #pragma unroll
        for (int j = 0; j < 8; ++j) {
            const float4 a = *(const float4*)&Asr[j * Ks + k];
            acc[j] = fmaf(a.x, w0, acc[j]);
            acc[j] = fmaf(a.y, w1, acc[j]);
            acc[j] = fmaf(a.z, w2, acc[j]);
            acc[j] = fmaf(a.w, w3, acc[j]);
        }
    }
    #pragma unroll
    for (int j = 0; j < 8; ++j) {
        int row = r0 + rg * 8 + j;
        if (row < n) C[(long)row * DD + c] = acc[j];
    }
}

// agg[i][c] = dinv[i]^2 * m[i][c] + bias[c] + sum_e norm[e]*m[src[e]][c]
__global__ __launch_bounds__(128) void agg_kernel(
    const float* __restrict__ m, const int* __restrict__ off,
    const int* __restrict__ src_s, const float* __restrict__ norm_s,
    const float* __restrict__ dinv, const float* __restrict__ bias,
    float* __restrict__ agg)
{
    int i = blockIdx.x, c = threadIdx.x;
    float di = dinv[i];
    float acc = di * di * m[(long)i * DD + c] + bias[c];
    int e = off[i], e1 = off[i + 1];
    for (; e + 4 <= e1; e += 4) {
        int j0 = src_s[e], j1 = src_s[e + 1], j2 = src_s[e + 2], j3 = src_s[e + 3];
        float n0 = norm_s[e], n1 = norm_s[e + 1], n2 = norm_s[e + 2], n3 = norm_s[e + 3];
        float m0 = m[(long)j0 * DD + c];
        float m1 = m[(long)j1 * DD + c];
        float m2 = m[(long)j2 * DD + c];
        float m3 = m[(long)j3 * DD + c];
        acc += n0 * m0; acc += n1 * m1; acc += n2 * m2; acc += n3 * m3;
    }
    for (; e < e1; ++e) acc += norm_s[e] * m[(long)src_s[e] * DD + c];
    agg[(long)i * DD + c] = acc;
}

// column sums + sumsq into acc[0..127]=sum, acc[128..255]=sumsq (pre-zeroed)
__global__ void stats_kernel(const float* __restrict__ agg, float* __restrict__ acc, int n) {
    int c = threadIdx.x & 127;
    int half = threadIdx.x >> 7;
    int rows_per_block = (n + gridDim.x - 1) / gridDim.x;
    int r0 = blockIdx.x * rows_per_block;
    int r1 = min(n, r0 + rows_per_block);
    float s = 0.0f, s2 = 0.0f;
    for (int r = r0 + half; r < r1; r += 2) {
        float v = agg[(long)r * DD + c];
        s += v; s2 += v * v;
    }
    __shared__ float sb[256], sb2[256];
    sb[threadIdx.x] = s; sb2[threadIdx.x] = s2;
    __syncthreads();
    if (threadIdx.x < 128) {
        atomicAdd(&acc[c], sb[threadIdx.x] + sb[threadIdx.x + 128]);
        atomicAdd(&acc[128 + c], sb2[threadIdx.x] + sb2[threadIdx.x + 128]);
    }
}

// h[idx] += relu((agg-mu)*rsqrt(var+eps)*gamma + beta)
__global__ void bnapply_kernel(float* __restrict__ h, const float* __restrict__ agg,
                               const float* __restrict__ acc,
                               const float* __restrict__ gamma, const float* __restrict__ beta,
                               int n) {
    long idx = (long)blockIdx.x * blockDim.x + threadIdx.x;
    if (idx >= (long)n * DD) return;
    int c = (int)(idx & 127);
    float inv_n = 1.0f / (float)n;
    float mu = acc[c] * inv_n;
    float var = acc[128 + c] * inv_n - mu * mu;
    float v = (agg[idx] - mu) * rsqrtf(var + BN_EPS) * gamma[c] + beta[c];
    h[idx] += fmaxf(v, 0.0f);
}

// ---- pooling: run-accumulated partial sums + finalize ----
__global__ void pool1_kernel(const float* __restrict__ h, const int* __restrict__ b32,
                             float* __restrict__ hgsum, int n) {
    int t = threadIdx.x;
    int c = t & 127, half = t >> 7;
    int rows_pb = (n + gridDim.x - 1) / gridDim.x;
    int r0 = blockIdx.x * rows_pb;
    int r1 = min(n, r0 + rows_pb);
    float acc = 0.0f;
    int gcur = -1;
    for (int r = r0 + half; r < r1; r += 2) {
        int g = b32[r];
        if (g != gcur) {
            if (gcur >= 0) atomicAdd(&hgsum[gcur * DD + c], acc);
            acc = 0.0f; gcur = g;
        }
        acc += h[(long)r * DD + c];
    }
    if (gcur >= 0) atomicAdd(&hgsum[gcur * DD + c], acc);
}

__device__ int lower_bound_i(const int* __restrict__ a, int n, int v) {
    int lo = 0, hi = n;
    while (lo < hi) {
        int mid = (lo + hi) >> 1;
        if (a[mid] < v) lo = mid + 1; else hi = mid;
    }
    return lo;
}

__global__ void poolfin_kernel(const float* __restrict__ hgsum, const int* __restrict__ b32,
                               float* __restrict__ hg, int n) {
    int g = blockIdx.x, c = threadIdx.x;
    int lo = lower_bound_i(b32, n, g);
    int hi = lower_bound_i(b32, n, g + 1);
    hg[g * DD + c] = hgsum[g * DD + c] / fmaxf((float)(hi - lo), 1.0f);
}

__global__ void readout_kernel(const float* __restrict__ hg,
                               const float* __restrict__ W1, const float* __restrict__ b1,
                               const float* __restrict__ W2, const float* __restrict__ b2,
                               const float* __restrict__ W3, const float* __restrict__ b3,
                               const int* __restrict__ flags, void* __restrict__ out) {
    int f32 = flags[2];
    int g = blockIdx.x;
    int t = threadIdx.x;
    __shared__ float hgs[DD];
    __shared__ float z1[DD / 2];
    __shared__ float z2[DD / 4];
    hgs[t] = hg[g * DD + t];
    __syncthreads();
    if (t < DD / 2) {
        float acc = b1[t];
        #pragma unroll 8
        for (int k = 0; k < DD; ++k) acc = fmaf(hgs[k], W1[k * (DD / 2) + t], acc);
        z1[t] = fmaxf(acc, 0.0f);
    }
    __syncthreads();
    if (t < DD / 4) {
        float acc = b2[t];
        #pragma unroll 8
        for (int k = 0; k < DD / 2; ++k) acc = fmaf(z1[k], W2[k * (DD / 4) + t], acc);
        z2[t] = fmaxf(acc, 0.0f);
    }
    __syncthreads();
    if (t < NC) {
        float acc = b3[t];
        #pragma unroll 8
        for (int k = 0; k < DD / 4; ++k) acc = fmaf(z2[k], W3[k * NC + t], acc);
        if (f32) ((float*)out)[g * NC + t] = acc;
        else     ((__hip_bfloat16*)out)[g * NC + t] = __float2bfloat16(acc);
    }
}

extern "C" void kernel_launch(void* const* d_in, const int* in_sizes, int n_in,
                              void* d_out, int out_size, void* d_ws, size_t ws_size,
                              hipStream_t stream) {
    const void* x      = d_in[0];
    const void* ei     = d_in[1];
    const void* batch  = d_in[2];
    const void* W_emb  = d_in[3];
    const void* b_emb  = d_in[4];
    const void* W_gcn  = d_in[5];
    const void* b_gcn  = d_in[6];
    const void* bn_g   = d_in[7];
    const void* bn_b   = d_in[8];
    const void* W_r1   = d_in[9];
    const void* b_r1   = d_in[10];
    const void* W_r2   = d_in[11];
    const void* b_r2   = d_in[12];
    const void* W_r3   = d_in[13];
    const void* b_r3   = d_in[14];

    char* p = (char*)d_ws;
    auto alloc = [&](size_t bytes) -> void* {
        void* r = (void*)p;
        p += (bytes + 255) & ~(size_t)255;
        return r;
    };
    int*   flags  = (int*)alloc(64 * 4);
    int*   deg    = (int*)alloc((size_t)NN * 4);
    int*   cursor = (int*)alloc((size_t)NN * 4);
    float* bnacc  = (float*)alloc((size_t)LL * 256 * 4);
    float* hgsum  = (float*)alloc((size_t)GG * DD * 4);
    int*   off    = (int*)alloc((size_t)(NN + 1) * 4);
    float* dinv   = (float*)alloc((size_t)NN * 4);
    int*   src32  = (int*)alloc((size_t)EE * 4);
    int*   dst32  = (int*)alloc((size_t)EE * 4);
    int*   b32    = (int*)alloc((size_t)NN * 4);
    int*   src_s  = (int*)alloc((size_t)EE * 4);
    float* norm_s = (float*)alloc((size_t)EE * 4);
    int*   bsum   = (int*)alloc(256 * 4);
    int*   boff   = (int*)alloc(256 * 4);
    float* h      = (float*)alloc((size_t)NN * DD * 4);
    float* m      = (float*)alloc((size_t)NN * DD * 4);
    float* agg    = (float*)alloc((size_t)NN * DD * 4);
    float* hg     = (float*)alloc((size_t)GG * DD * 4);
    // canonical fp32 params
    float* w_emb32 = (float*)alloc((size_t)KS_EMB * DD * 4);   // zero-padded to 148 rows
    float* b_emb32 = (float*)alloc(DD * 4);
    float* w_gcn32 = (float*)alloc((size_t)LL * DD * DD * 4);
    float* b_gcn32 = (float*)alloc((size_t)LL * DD * 4);
    float* bng32   = (float*)alloc((size_t)LL * DD * 4);
    float* bnb32   = (float*)alloc((size_t)LL * DD * 4);
    float* wr1     = (float*)alloc((size_t)DD * (DD / 2) * 4);
    float* br1     = (float*)alloc((DD / 2) * 4);
    float* wr2     = (float*)alloc((size_t)(DD / 2) * (DD / 4) * 4);
    float* br2     = (float*)alloc((DD / 4) * 4);
    float* wr3     = (float*)alloc((size_t)(DD / 4) * NC * 4);
    float* br3     = (float*)alloc(NC * 4);

    detect_kernel<<<1, 64, 0, stream>>>(ei, batch, W_emb, flags);
    init_kernel<<<(NN + 255) / 256, 256, 0, stream>>>(deg, cursor, bnacc, hgsum);

    Params12 P;
    P.p[0]  = { W_emb, w_emb32, DIN * DD, KS_EMB * DD };
    P.p[1]  = { b_emb, b_emb32, DD, DD };
    P.p[2]  = { W_gcn, w_gcn32, LL * DD * DD, LL * DD * DD };
    P.p[3]  = { b_gcn, b_gcn32, LL * DD, LL * DD };
    P.p[4]  = { bn_g,  bng32,   LL * DD, LL * DD };
    P.p[5]  = { bn_b,  bnb32,   LL * DD, LL * DD };
    P.p[6]  = { W_r1,  wr1,     DD * (DD / 2), DD * (DD / 2) };
    P.p[7]  = { b_r1,  br1,     DD / 2, DD / 2 };
    P.p[8]  = { W_r2,  wr2,     (DD / 2) * (DD / 4), (DD / 2) * (DD / 4) };
    P.p[9]  = { b_r2,  br2,     DD / 4, DD / 4 };
    P.p[10] = { W_r3,  wr3,     (DD / 4) * NC, (DD / 4) * NC };
    P.p[11] = { b_r3,  br3,     NC, NC };
    dim3 cgrid((LL * DD * DD + 255) / 256, 12);
    conv_params_kernel<<<cgrid, 256, 0, stream>>>(P, flags);

    conv_idx_deg_kernel<<<(EE + 255) / 256, 256, 0, stream>>>(ei, flags, src32, dst32, deg);
    conv_batch_kernel<<<(NN + 255) / 256, 256, 0, stream>>>(batch, flags, b32);
    dinv_kernel<<<(NN + 255) / 256, 256, 0, stream>>>(deg, dinv, NN);

    int nb = (NN + 255) / 256;  // 196
    scan1_kernel<<<nb, 256, 0, stream>>>(deg, off, bsum, NN);
    scan2_kernel<<<1, 256, 0, stream>>>(bsum, boff, off + NN, nb);
    scan3_kernel<<<nb, 256, 0, stream>>>(off, boff, NN);

    scatter_kernel<<<(EE + 255) / 256, 256, 0, stream>>>(src32, dst32, off, cursor, dinv,
                                                         src_s, norm_s, EE);

    int ngemm = (NN + 15) / 16;  // 3125
    // embedding: A = x (native dtype), K=146 (staged to 148), W zero-padded to 148 rows
    gemm_kernel<<<ngemm, 256, 0, stream>>>(x, DIN, KS_EMB, DIN, 1,
                                           w_emb32, b_emb32, 1, flags, h, NN);

    for (int l = 0; l < LL; ++l) {
        gemm_kernel<<<ngemm, 256, 0, stream>>>(h, DD, DD, DD, 0,
                                               w_gcn32 + (size_t)l * DD * DD, nullptr, 0,
                                               flags, m, NN);
        agg_kernel<<<NN, 128, 0, stream>>>(m, off, src_s, norm_s, dinv,
                                           b_gcn32 + l * DD, agg);
        stats_kernel<<<512, 256, 0, stream>>>(agg, bnacc + l * 256, NN);
        bnapply_kernel<<<(NN * DD + 255) / 256, 256, 0, stream>>>(h, agg, bnacc + l * 256,
                                                                  bng32 + l * DD, bnb32 + l * DD, NN);
    }

    pool1_kernel<<<512, 256, 0, stream>>>(h, b32, hgsum, NN);
    poolfin_kernel<<<GG, 128, 0, stream>>>(hgsum, b32, hg, NN);
    readout_kernel<<<GG, DD, 0, stream>>>(hg, wr1, br1, wr2, br2, wr3, br3, flags, d_out);
}

// Round 4
// 690.244 us; speedup vs baseline: 2.3058x; 1.2107x over previous
//
#include <hip/hip_runtime.h>
#include <hip/hip_bf16.h>

// Problem constants (fixed by the reference)
#define NN 50000
#define EE 800000
#define DIN 146
#define DD 128
#define GG 64
#define LL 4
#define NC 10
#define BN_EPS 1e-5f

#define KP_EMB 160    // 146 padded to multiple of 32
#define AST_EMB 168   // LDS A stride (elements) for emb  (16B-aligned, breaks bank stride)
#define AST_L   136   // LDS A stride for layer gemms

typedef __attribute__((ext_vector_type(8))) short bf16x8;
typedef __attribute__((ext_vector_type(4))) float f32x4;

__device__ __forceinline__ float bf2f(__hip_bfloat16 v) { return __bfloat162float(v); }
__device__ __forceinline__ float loadf(const void* p, long i, int f32) {
    return f32 ? ((const float*)p)[i] : bf2f(((const __hip_bfloat16*)p)[i]);
}
__device__ __forceinline__ unsigned short f2bf_bits(float f) {
    __hip_bfloat16 h = __float2bfloat16(f);
    return *(unsigned short*)&h;
}
__device__ __forceinline__ float bfu2f(unsigned short u) {
    return __uint_as_float((unsigned)u << 16);
}

// flags[0]=edge_index int64, flags[1]=batch int64, flags[2]=floats are f32
__global__ void detect_kernel(const void* ei, const void* batch, const void* Wemb,
                              int* __restrict__ flags) {
    __shared__ int s_edge_nz, s_batch_nz, s_f32_cnt;
    int t = threadIdx.x;  // 64 threads
    if (t == 0) { s_edge_nz = 0; s_batch_nz = 0; s_f32_cnt = 0; }
    __syncthreads();
    {   const int* w = (const int*)ei;
        long j = ((long)t * ((2L * EE) / 64)) | 1;
        if (w[j] != 0) atomicAdd(&s_edge_nz, 1);
    }
    {   const int* w = (const int*)batch;
        long j = ((long)(NN / 2) + (long)t * ((NN / 2) / 64)) | 1;
        if (j < NN && w[j] != 0) atomicAdd(&s_batch_nz, 1);
    }
    {   const unsigned short* w = (const unsigned short*)Wemb;
        unsigned short v = w[2 * t];
        int ex = (v >> 7) & 0xFF;
        if (v != 0 && ex >= 128) atomicAdd(&s_f32_cnt, 1);
    }
    __syncthreads();
    if (t == 0) {
        flags[0] = (s_edge_nz == 0) ? 1 : 0;
        flags[1] = (s_batch_nz == 0) ? 1 : 0;
        flags[2] = (s_f32_cnt >= 8) ? 1 : 0;
    }
}

// ---- canonicalize small params to fp32 ----
struct Param { const void* src; float* dst; int src_n; int dst_n; };
struct Params12 { Param p[12]; };

__global__ void conv_params_kernel(Params12 P, const int* __restrict__ flags) {
    int f32 = flags[2];
    const Param& e = P.p[blockIdx.y];
    int idx = blockIdx.x * 256 + threadIdx.x;
    if (idx < e.dst_n)
        e.dst[idx] = (idx < e.src_n) ? loadf(e.src, idx, f32) : 0.0f;
}

// ---- canonicalize weights to bf16, TRANSPOSED [n=128][k=Kpad], zero-padded ----
struct WtDesc { const void* src; long src_off; unsigned short* dst; int K; int Kpad; };
struct WtDescs5 { WtDesc p[5]; };

__global__ void conv_wt_kernel(WtDescs5 P, const int* __restrict__ flags) {
    int f32 = flags[2];
    const WtDesc& e = P.p[blockIdx.y];
    int idx = blockIdx.x * 256 + threadIdx.x;
    if (idx >= 128 * e.Kpad) return;
    int n = idx / e.Kpad, k = idx - n * e.Kpad;
    float v = (k < e.K) ? loadf(e.src, e.src_off + (long)k * DD + n, f32) : 0.0f;
    e.dst[idx] = f2bf_bits(v);
}

// zero deg/cursor/bnacc/hgsum
__global__ void init_kernel(int* __restrict__ deg, int* __restrict__ cursor,
                            float* __restrict__ bnacc, float* __restrict__ hgsum) {
    int i = blockIdx.x * blockDim.x + threadIdx.x;
    if (i < NN) { deg[i] = 0; cursor[i] = 0; }
    if (i < LL * 256) bnacc[i] = 0.0f;
    if (i < GG * DD) hgsum[i] = 0.0f;
}

__global__ void conv_idx_deg_kernel(const void* ei, const int* __restrict__ flags,
                                    int* __restrict__ src32, int* __restrict__ dst32,
                                    int* __restrict__ deg) {
    int e = blockIdx.x * blockDim.x + threadIdx.x;
    if (e >= EE) return;
    const int* w = (const int*)ei;
    int s, d;
    if (flags[0]) { s = w[2L * e]; d = w[2L * (EE + e)]; }
    else          { s = w[e];      d = w[EE + e]; }
    src32[e] = s; dst32[e] = d;
    if ((unsigned)d < (unsigned)NN) atomicAdd(&deg[d], 1);
}

__global__ void conv_batch_kernel(const void* b, const int* __restrict__ flags,
                                  int* __restrict__ b32) {
    int i = blockIdx.x * blockDim.x + threadIdx.x;
    if (i >= NN) return;
    b32[i] = flags[1] ? ((const int*)b)[2L * i] : ((const int*)b)[i];
}

__global__ void dinv_kernel(const int* __restrict__ deg, float* __restrict__ dinv, int n) {
    int i = blockIdx.x * blockDim.x + threadIdx.x;
    if (i < n) dinv[i] = rsqrtf((float)(deg[i] + 1));  // +1 self-loop
}

// ---- 3-phase exclusive scan ----
__global__ void scan1_kernel(const int* __restrict__ cnt, int* __restrict__ off,
                             int* __restrict__ bsum, int n) {
    int t = threadIdx.x;
    int i = blockIdx.x * 256 + t;
    int v = (i < n) ? cnt[i] : 0;
    int lane = t & 63, w = t >> 6;
    int x = v;
    #pragma unroll
    for (int s = 1; s < 64; s <<= 1) {
        int y = __shfl_up(x, s, 64);
        if (lane >= s) x += y;
    }
    __shared__ int wsum[4];
    if (lane == 63) wsum[w] = x;
    __syncthreads();
    if (t == 0) {
        int a = 0;
        #pragma unroll
        for (int k = 0; k < 4; ++k) { int tmp = wsum[k]; wsum[k] = a; a += tmp; }
        bsum[blockIdx.x] = a;
    }
    __syncthreads();
    int excl = x - v + wsum[w];
    if (i < n) off[i] = excl;
}

__global__ void scan2_kernel(int* __restrict__ bsum, int* __restrict__ boff,
                             int* __restrict__ off_last, int nb) {
    int t = threadIdx.x;  // 256
    int v = (t < nb) ? bsum[t] : 0;
    int lane = t & 63, w = t >> 6;
    int x = v;
    #pragma unroll
    for (int s = 1; s < 64; s <<= 1) {
        int y = __shfl_up(x, s, 64);
        if (lane >= s) x += y;
    }
    __shared__ int wsum[4];
    if (lane == 63) wsum[w] = x;
    __syncthreads();
    __shared__ int total_s;
    if (t == 0) {
        int a = 0;
        #pragma unroll
        for (int k = 0; k < 4; ++k) { int tmp = wsum[k]; wsum[k] = a; a += tmp; }
        total_s = a;
    }
    __syncthreads();
    if (t < nb) boff[t] = x - v + wsum[w];
    if (t == 0) *off_last = total_s;
}

__global__ void scan3_kernel(int* __restrict__ off, const int* __restrict__ boff, int n) {
    int i = blockIdx.x * 256 + threadIdx.x;
    if (i < n) off[i] += boff[blockIdx.x];
}

__global__ void scatter_kernel(const int* __restrict__ src, const int* __restrict__ dst,
                               const int* __restrict__ off, int* __restrict__ cursor,
                               const float* __restrict__ dinv,
                               int* __restrict__ src_s, float* __restrict__ norm_s, int E) {
    int e = blockIdx.x * blockDim.x + threadIdx.x;
    if (e >= E) return;
    int s = src[e], d = dst[e];
    if ((unsigned)s >= (unsigned)NN || (unsigned)d >= (unsigned)NN) return;
    int pos = off[d] + atomicAdd(&cursor[d], 1);
    src_s[pos] = s;
    norm_s[pos] = dinv[s] * dinv[d];
}

// ---- MFMA GEMMs: C[n x 128] = A[n x K] * W[K x 128] ----
// Verified gfx950 16x16x32 bf16 layouts:
//   A frag: m=lane&15, k=quad*8+j   B frag (from W^T): n=lane&15, k=quad*8+j
//   C/D:    col=lane&15, row=quad*4+reg

// embedding: A = x (native dtype, K=146 padded to 160), out h fp32 + hb bf16, +bias
__global__ __launch_bounds__(256) void emb_gemm_kernel(
    const void* __restrict__ x, const int* __restrict__ flags,
    const unsigned short* __restrict__ Wt,   // [128][160] bf16 transposed
    const float* __restrict__ bias,
    float* __restrict__ h, unsigned short* __restrict__ hb, int n)
{
    __shared__ unsigned short As[128 * AST_EMB];
    int t = threadIdx.x;
    int r0 = blockIdx.x * 128;
    int f32 = flags[2];
    for (int idx = t; idx < 128 * KP_EMB; idx += 256) {
        int row = idx / KP_EMB, k = idx - row * KP_EMB;
        int r = r0 + row;
        float v = 0.0f;
        if (r < n && k < DIN) v = loadf(x, (long)r * DIN + k, f32);
        As[row * AST_EMB + k] = f2bf_bits(v);
    }
    __syncthreads();
    int lane = t & 63, w = t >> 6;
    int m = lane & 15, quad = lane >> 4;
    int rl = w * 32;
    bf16x8 a[2][5];
    #pragma unroll
    for (int rt = 0; rt < 2; ++rt)
        #pragma unroll
        for (int c = 0; c < 5; ++c)
            a[rt][c] = *(const bf16x8*)(As + (rl + rt * 16 + m) * AST_EMB + c * 32 + quad * 8);
    f32x4 acc[2][8];
    #pragma unroll
    for (int t8 = 0; t8 < 8; ++t8) {
        float bv = bias[t8 * 16 + m];
        f32x4 ai = {bv, bv, bv, bv};
        acc[0][t8] = ai; acc[1][t8] = ai;
    }
    #pragma unroll
    for (int t8 = 0; t8 < 8; ++t8) {
        #pragma unroll
        for (int c = 0; c < 5; ++c) {
            bf16x8 b = *(const bf16x8*)(Wt + (long)(t8 * 16 + m) * KP_EMB + c * 32 + quad * 8);
            acc[0][t8] = __builtin_amdgcn_mfma_f32_16x16x32_bf16(a[0][c], b, acc[0][t8], 0, 0, 0);
            acc[1][t8] = __builtin_amdgcn_mfma_f32_16x16x32_bf16(a[1][c], b, acc[1][t8], 0, 0, 0);
        }
    }
    #pragma unroll
    for (int rt = 0; rt < 2; ++rt)
        #pragma unroll
        for (int t8 = 0; t8 < 8; ++t8)
            #pragma unroll
            for (int rg = 0; rg < 4; ++rg) {
                int row = r0 + rl + rt * 16 + quad * 4 + rg;
                int col = t8 * 16 + m;
                if (row < n) {
                    float v = acc[rt][t8][rg];
                    h[(long)row * DD + col] = v;
                    hb[(long)row * DD + col] = f2bf_bits(v);
                }
            }
}

// plain: A = hb (bf16 global), out m bf16
__global__ __launch_bounds__(256) void gemm_plain_kernel(
    const unsigned short* __restrict__ Ab,   // [n][128] bf16
    const unsigned short* __restrict__ Wt,   // [128][128] bf16 transposed
    unsigned short* __restrict__ Mb, int n)
{
    int t = threadIdx.x;
    int r0 = blockIdx.x * 128;
    int lane = t & 63, w = t >> 6;
    int m = lane & 15, quad = lane >> 4;
    int rbase = r0 + w * 32;
    bf16x8 a[2][4];
    #pragma unroll
    for (int rt = 0; rt < 2; ++rt)
        #pragma unroll
        for (int c = 0; c < 4; ++c) {
            int rr = rbase + rt * 16 + m; if (rr > n - 1) rr = n - 1;
            a[rt][c] = *(const bf16x8*)(Ab + (long)rr * DD + c * 32 + quad * 8);
        }
    f32x4 acc[2][8];
    #pragma unroll
    for (int t8 = 0; t8 < 8; ++t8) {
        f32x4 z = {0.f, 0.f, 0.f, 0.f};
        acc[0][t8] = z; acc[1][t8] = z;
    }
    #pragma unroll
    for (int t8 = 0; t8 < 8; ++t8) {
        #pragma unroll
        for (int c = 0; c < 4; ++c) {
            bf16x8 b = *(const bf16x8*)(Wt + (long)(t8 * 16 + m) * DD + c * 32 + quad * 8);
            acc[0][t8] = __builtin_amdgcn_mfma_f32_16x16x32_bf16(a[0][c], b, acc[0][t8], 0, 0, 0);
            acc[1][t8] = __builtin_amdgcn_mfma_f32_16x16x32_bf16(a[1][c], b, acc[1][t8], 0, 0, 0);
        }
    }
    #pragma unroll
    for (int rt = 0; rt < 2; ++rt)
        #pragma unroll
        for (int t8 = 0; t8 < 8; ++t8)
            #pragma unroll
            for (int rg = 0; rg < 4; ++rg) {
                int row = rbase + rt * 16 + quad * 4 + rg;
                int col = t8 * 16 + m;
                if (row < n) Mb[(long)row * DD + col] = f2bf_bits(acc[rt][t8][rg]);
            }
}

// fused: h += relu(bn(agg)) in-place (fp32), bf16 tile -> LDS -> MFMA -> m bf16
__global__ __launch_bounds__(256) void gemm_fused_kernel(
    const float* __restrict__ agg, float* __restrict__ h,
    const float* __restrict__ bnacc, const float* __restrict__ gamma,
    const float* __restrict__ beta,
    const unsigned short* __restrict__ Wt, unsigned short* __restrict__ Mb, int n)
{
    __shared__ unsigned short As[128 * AST_L];
    int t = threadIdx.x;
    int r0 = blockIdx.x * 128;
    {
        int col = t & 127, hi2 = t >> 7;
        float inv_n = 1.0f / (float)n;
        float mu = bnacc[col] * inv_n;
        float var = bnacc[128 + col] * inv_n - mu * mu;
        float rs = rsqrtf(var + BN_EPS) * gamma[col];
        float bt = beta[col];
        #pragma unroll 4
        for (int i = 0; i < 64; ++i) {
            int row = i * 2 + hi2;
            int r = r0 + row;
            float hv = 0.0f;
            if (r < n) {
                long g = (long)r * DD + col;
                float v = (agg[g] - mu) * rs + bt;
                hv = h[g] + fmaxf(v, 0.0f);
                h[g] = hv;
            }
            As[row * AST_L + col] = f2bf_bits(hv);
        }
    }
    __syncthreads();
    int lane = t & 63, w = t >> 6;
    int m = lane & 15, quad = lane >> 4;
    int rl = w * 32;
    bf16x8 a[2][4];
    #pragma unroll
    for (int rt = 0; rt < 2; ++rt)
        #pragma unroll
        for (int c = 0; c < 4; ++c)
            a[rt][c] = *(const bf16x8*)(As + (rl + rt * 16 + m) * AST_L + c * 32 + quad * 8);
    f32x4 acc[2][8];
    #pragma unroll
    for (int t8 = 0; t8 < 8; ++t8) {
        f32x4 z = {0.f, 0.f, 0.f, 0.f};
        acc[0][t8] = z; acc[1][t8] = z;
    }
    #pragma unroll
    for (int t8 = 0; t8 < 8; ++t8) {
        #pragma unroll
        for (int c = 0; c < 4; ++c) {
            bf16x8 b = *(const bf16x8*)(Wt + (long)(t8 * 16 + m) * DD + c * 32 + quad * 8);
            acc[0][t8] = __builtin_amdgcn_mfma_f32_16x16x32_bf16(a[0][c], b, acc[0][t8], 0, 0, 0);
            acc[1][t8] = __builtin_amdgcn_mfma_f32_16x16x32_bf16(a[1][c], b, acc[1][t8], 0, 0, 0);
        }
    }
    #pragma unroll
    for (int rt = 0; rt < 2; ++rt)
        #pragma unroll
        for (int t8 = 0; t8 < 8; ++t8)
            #pragma unroll
            for (int rg = 0; rg < 4; ++rg) {
                int row = r0 + rl + rt * 16 + quad * 4 + rg;
                int col = t8 * 16 + m;
                if (row < n) Mb[(long)row * DD + col] = f2bf_bits(acc[rt][t8][rg]);
            }
}

// agg[i][c] = dinv[i]^2 * m[i][c] + bias[c] + sum_e norm[e]*m[src[e]][c]  (m bf16)
__global__ __launch_bounds__(128) void agg_kernel(
    const unsigned short* __restrict__ mb, const int* __restrict__ off,
    const int* __restrict__ src_s, const float* __restrict__ norm_s,
    const float* __restrict__ dinv, const float* __restrict__ bias,
    float* __restrict__ agg)
{
    int i = blockIdx.x, c = threadIdx.x;
    float di = dinv[i];
    float acc = di * di * bfu2f(mb[(long)i * DD + c]) + bias[c];
    int e = off[i], e1 = off[i + 1];
    for (; e + 4 <= e1; e += 4) {
        int j0 = src_s[e], j1 = src_s[e + 1], j2 = src_s[e + 2], j3 = src_s[e + 3];
        float n0 = norm_s[e], n1 = norm_s[e + 1], n2 = norm_s[e + 2], n3 = norm_s[e + 3];
        float m0 = bfu2f(mb[(long)j0 * DD + c]);
        float m1 = bfu2f(mb[(long)j1 * DD + c]);
        float m2 = bfu2f(mb[(long)j2 * DD + c]);
        float m3 = bfu2f(mb[(long)j3 * DD + c]);
        acc += n0 * m0; acc += n1 * m1; acc += n2 * m2; acc += n3 * m3;
    }
    for (; e < e1; ++e) acc += norm_s[e] * bfu2f(mb[(long)src_s[e] * DD + c]);
    agg[(long)i * DD + c] = acc;
}

// column sums + sumsq into acc[0..127]=sum, acc[128..255]=sumsq (pre-zeroed)
__global__ void stats_kernel(const float* __restrict__ agg, float* __restrict__ acc, int n) {
    int c = threadIdx.x & 127;
    int half = threadIdx.x >> 7;
    int rows_per_block = (n + gridDim.x - 1) / gridDim.x;
    int r0 = blockIdx.x * rows_per_block;
    int r1 = min(n, r0 + rows_per_block);
    float s = 0.0f, s2 = 0.0f;
    for (int r = r0 + half; r < r1; r += 2) {
        float v = agg[(long)r * DD + c];
        s += v; s2 += v * v;
    }
    __shared__ float sb[256], sb2[256];
    sb[threadIdx.x] = s; sb2[threadIdx.x] = s2;
    __syncthreads();
    if (threadIdx.x < 128) {
        atomicAdd(&acc[c], sb[threadIdx.x] + sb[threadIdx.x + 128]);
        atomicAdd(&acc[128 + c], sb2[threadIdx.x] + sb2[threadIdx.x + 128]);
    }
}

// pooling with fused final BN+relu+residual: sum_g( h[r] + relu(bn(agg[r])) )
__global__ void pool1_kernel(const float* __restrict__ h, const float* __restrict__ agg,
                             const float* __restrict__ bnacc,
                             const float* __restrict__ gamma, const float* __restrict__ beta,
                             const int* __restrict__ b32, float* __restrict__ hgsum, int n) {
    int t = threadIdx.x;
    int c = t & 127, half = t >> 7;
    float inv_n = 1.0f / (float)n;
    float mu = bnacc[c] * inv_n;
    float var = bnacc[128 + c] * inv_n - mu * mu;
    float rs = rsqrtf(var + BN_EPS) * gamma[c];
    float bt = beta[c];
    int rows_pb = (n + gridDim.x - 1) / gridDim.x;
    int r0 = blockIdx.x * rows_pb;
    int r1 = min(n, r0 + rows_pb);
    float acc = 0.0f;
    int gcur = -1;
    for (int r = r0 + half; r < r1; r += 2) {
        int g = b32[r];
        if (g != gcur) {
            if (gcur >= 0) atomicAdd(&hgsum[gcur * DD + c], acc);
            acc = 0.0f; gcur = g;
        }
        long ix = (long)r * DD + c;
        float v = (agg[ix] - mu) * rs + bt;
        acc += h[ix] + fmaxf(v, 0.0f);
    }
    if (gcur >= 0) atomicAdd(&hgsum[gcur * DD + c], acc);
}

__device__ int lower_bound_i(const int* __restrict__ a, int n, int v) {
    int lo = 0, hi = n;
    while (lo < hi) {
        int mid = (lo + hi) >> 1;
        if (a[mid] < v) lo = mid + 1; else hi = mid;
    }
    return lo;
}

__global__ void poolfin_kernel(const float* __restrict__ hgsum, const int* __restrict__ b32,
                               float* __restrict__ hg, int n) {
    int g = blockIdx.x, c = threadIdx.x;
    int lo = lower_bound_i(b32, n, g);
    int hi = lower_bound_i(b32, n, g + 1);
    hg[g * DD + c] = hgsum[g * DD + c] / fmaxf((float)(hi - lo), 1.0f);
}

__global__ void readout_kernel(const float* __restrict__ hg,
                               const float* __restrict__ W1, const float* __restrict__ b1,
                               const float* __restrict__ W2, const float* __restrict__ b2,
                               const float* __restrict__ W3, const float* __restrict__ b3,
                               const int* __restrict__ flags, void* __restrict__ out) {
    int f32 = flags[2];
    int g = blockIdx.x;
    int t = threadIdx.x;
    __shared__ float hgs[DD];
    __shared__ float z1[DD / 2];
    __shared__ float z2[DD / 4];
    hgs[t] = hg[g * DD + t];
    __syncthreads();
    if (t < DD / 2) {
        float acc = b1[t];
        #pragma unroll 8
        for (int k = 0; k < DD; ++k) acc = fmaf(hgs[k], W1[k * (DD / 2) + t], acc);
        z1[t] = fmaxf(acc, 0.0f);
    }
    __syncthreads();
    if (t < DD / 4) {
        float acc = b2[t];
        #pragma unroll 8
        for (int k = 0; k < DD / 2; ++k) acc = fmaf(z1[k], W2[k * (DD / 4) + t], acc);
        z2[t] = fmaxf(acc, 0.0f);
    }
    __syncthreads();
    if (t < NC) {
        float acc = b3[t];
        #pragma unroll 8
        for (int k = 0; k < DD / 4; ++k) acc = fmaf(z2[k], W3[k * NC + t], acc);
        if (f32) ((float*)out)[g * NC + t] = acc;
        else     ((__hip_bfloat16*)out)[g * NC + t] = __float2bfloat16(acc);
    }
}

extern "C" void kernel_launch(void* const* d_in, const int* in_sizes, int n_in,
                              void* d_out, int out_size, void* d_ws, size_t ws_size,
                              hipStream_t stream) {
    const void* x      = d_in[0];
    const void* ei     = d_in[1];
    const void* batch  = d_in[2];
    const void* W_emb  = d_in[3];
    const void* b_emb  = d_in[4];
    const void* W_gcn  = d_in[5];
    const void* b_gcn  = d_in[6];
    const void* bn_g   = d_in[7];
    const void* bn_b   = d_in[8];
    const void* W_r1   = d_in[9];
    const void* b_r1   = d_in[10];
    const void* W_r2   = d_in[11];
    const void* b_r2   = d_in[12];
    const void* W_r3   = d_in[13];
    const void* b_r3   = d_in[14];

    char* p = (char*)d_ws;
    auto alloc = [&](size_t bytes) -> void* {
        void* r = (void*)p;
        p += (bytes + 255) & ~(size_t)255;
        return r;
    };
    int*   flags  = (int*)alloc(64 * 4);
    int*   deg    = (int*)alloc((size_t)NN * 4);
    int*   cursor = (int*)alloc((size_t)NN * 4);
    float* bnacc  = (float*)alloc((size_t)LL * 256 * 4);
    float* hgsum  = (float*)alloc((size_t)GG * DD * 4);
    int*   off    = (int*)alloc((size_t)(NN + 1) * 4);
    float* dinv   = (float*)alloc((size_t)NN * 4);
    int*   src32  = (int*)alloc((size_t)EE * 4);
    int*   dst32  = (int*)alloc((size_t)EE * 4);
    int*   b32    = (int*)alloc((size_t)NN * 4);
    int*   src_s  = (int*)alloc((size_t)EE * 4);
    float* norm_s = (float*)alloc((size_t)EE * 4);
    int*   bsum   = (int*)alloc(256 * 4);
    int*   boff   = (int*)alloc(256 * 4);
    float* h      = (float*)alloc((size_t)NN * DD * 4);
    unsigned short* hb = (unsigned short*)alloc((size_t)NN * DD * 2);
    unsigned short* mb = (unsigned short*)alloc((size_t)NN * DD * 2);
    float* agg    = (float*)alloc((size_t)NN * DD * 4);
    float* hg     = (float*)alloc((size_t)GG * DD * 4);
    // canonical params
    unsigned short* wt_emb = (unsigned short*)alloc((size_t)DD * KP_EMB * 2);  // [n][k] bf16
    unsigned short* wt_gcn = (unsigned short*)alloc((size_t)LL * DD * DD * 2); // [l][n][k] bf16
    float* b_emb32 = (float*)alloc(DD * 4);
    float* b_gcn32 = (float*)alloc((size_t)LL * DD * 4);
    float* bng32   = (float*)alloc((size_t)LL * DD * 4);
    float* bnb32   = (float*)alloc((size_t)LL * DD * 4);
    float* wr1     = (float*)alloc((size_t)DD * (DD / 2) * 4);
    float* br1     = (float*)alloc((DD / 2) * 4);
    float* wr2     = (float*)alloc((size_t)(DD / 2) * (DD / 4) * 4);
    float* br2     = (float*)alloc((DD / 4) * 4);
    float* wr3     = (float*)alloc((size_t)(DD / 4) * NC * 4);
    float* br3     = (float*)alloc(NC * 4);

    detect_kernel<<<1, 64, 0, stream>>>(ei, batch, W_emb, flags);
    init_kernel<<<(NN + 255) / 256, 256, 0, stream>>>(deg, cursor, bnacc, hgsum);

    Params12 P;
    P.p[0]  = { b_emb, b_emb32, DD, DD };
    P.p[1]  = { b_gcn, b_gcn32, LL * DD, LL * DD };
    P.p[2]  = { bn_g,  bng32,   LL * DD, LL * DD };
    P.p[3]  = { bn_b,  bnb32,   LL * DD, LL * DD };
    P.p[4]  = { W_r1,  wr1,     DD * (DD / 2), DD * (DD / 2) };
    P.p[5]  = { b_r1,  br1,     DD / 2, DD / 2 };
    P.p[6]  = { W_r2,  wr2,     (DD / 2) * (DD / 4), (DD / 2) * (DD / 4) };
    P.p[7]  = { b_r2,  br2,     DD / 4, DD / 4 };
    P.p[8]  = { W_r3,  wr3,     (DD / 4) * NC, (DD / 4) * NC };
    P.p[9]  = { b_r3,  br3,     NC, NC };
    P.p[10] = { b_r3,  br3,     0, 0 };
    P.p[11] = { b_r3,  br3,     0, 0 };
    dim3 cgrid((DD * (DD / 2) + 255) / 256, 12);
    conv_params_kernel<<<cgrid, 256, 0, stream>>>(P, flags);

    WtDescs5 W;
    W.p[0] = { W_emb, 0,                wt_emb,                DIN, KP_EMB };
    W.p[1] = { W_gcn, 0L * DD * DD,     wt_gcn + 0L * DD * DD, DD,  DD };
    W.p[2] = { W_gcn, 1L * DD * DD,     wt_gcn + 1L * DD * DD, DD,  DD };
    W.p[3] = { W_gcn, 2L * DD * DD,     wt_gcn + 2L * DD * DD, DD,  DD };
    W.p[4] = { W_gcn, 3L * DD * DD,     wt_gcn + 3L * DD * DD, DD,  DD };
    dim3 wgrid((128 * KP_EMB + 255) / 256, 5);
    conv_wt_kernel<<<wgrid, 256, 0, stream>>>(W, flags);

    conv_idx_deg_kernel<<<(EE + 255) / 256, 256, 0, stream>>>(ei, flags, src32, dst32, deg);
    conv_batch_kernel<<<(NN + 255) / 256, 256, 0, stream>>>(batch, flags, b32);
    dinv_kernel<<<(NN + 255) / 256, 256, 0, stream>>>(deg, dinv, NN);

    int nb = (NN + 255) / 256;  // 196
    scan1_kernel<<<nb, 256, 0, stream>>>(deg, off, bsum, NN);
    scan2_kernel<<<1, 256, 0, stream>>>(bsum, boff, off + NN, nb);
    scan3_kernel<<<nb, 256, 0, stream>>>(off, boff, NN);

    scatter_kernel<<<(EE + 255) / 256, 256, 0, stream>>>(src32, dst32, off, cursor, dinv,
                                                         src_s, norm_s, EE);

    int ngemm = (NN + 127) / 128;  // 391
    emb_gemm_kernel<<<ngemm, 256, 0, stream>>>(x, flags, wt_emb, b_emb32, h, hb, NN);

    for (int l = 0; l < LL; ++l) {
        if (l == 0) {
            gemm_plain_kernel<<<ngemm, 256, 0, stream>>>(hb, wt_gcn, mb, NN);
        } else {
            gemm_fused_kernel<<<ngemm, 256, 0, stream>>>(
                agg, h, bnacc + (l - 1) * 256, bng32 + (l - 1) * DD, bnb32 + (l - 1) * DD,
                wt_gcn + (size_t)l * DD * DD, mb, NN);
        }
        agg_kernel<<<NN, 128, 0, stream>>>(mb, off, src_s, norm_s, dinv,
                                           b_gcn32 + l * DD, agg);
        stats_kernel<<<512, 256, 0, stream>>>(agg, bnacc + l * 256, NN);
    }

    pool1_kernel<<<512, 256, 0, stream>>>(h, agg, bnacc + (LL - 1) * 256,
                                          bng32 + (LL - 1) * DD, bnb32 + (LL - 1) * DD,
                                          b32, hgsum, NN);
    poolfin_kernel<<<GG, 128, 0, stream>>>(hgsum, b32, hg, NN);
    readout_kernel<<<GG, DD, 0, stream>>>(hg, wr1, br1, wr2, br2, wr3, br3, flags, d_out);
}